// Round 2
// 1221.985 us; speedup vs baseline: 1.0278x; 1.0278x over previous
//
#include <hip/hip_runtime.h>
#include <hip/hip_bf16.h>
#include <math.h>

// Problem constants
#define B_   32
#define T_   128
#define TE_  128
#define U_   64
#define E_   512
#define V_   32000
#define G_   256   // 4*U

typedef __attribute__((ext_vector_type(8))) short  short8x;
typedef __attribute__((ext_vector_type(4))) float  f32x4;
typedef __attribute__((ext_vector_type(4))) unsigned short u16x4;

__device__ inline unsigned short f2bf(float x) {
    union { float f; unsigned int u; } v; v.f = x;
    unsigned int u = v.u;
    u = (u + 0x7FFFu + ((u >> 16) & 1u)) >> 16;   // round-to-nearest-even
    return (unsigned short)u;
}

// ---------------------------------------------------------------------------
// K1: xz[row, g] = sum_e emb[dec[row], e] * Wx[e, g] + bias[g]
// 16 rows per block, 256 threads (col g). emb rows staged in LDS;
// Wx read once per block (L2-resident across 256 blocks).
// e-loop vectorized: float4 LDS reads (4x fewer ds instructions; this kernel
// runs at 1 block/CU so the ds pipe is the serial bottleneck).
// ---------------------------------------------------------------------------
__global__ void embed_xz_kernel(const int* __restrict__ dec,
                                const float* __restrict__ emb,
                                const float* __restrict__ Wx,
                                const float* __restrict__ bias,
                                float* __restrict__ xz) {
    __shared__ float xs[16][E_];           // 32 KB
    int tid = threadIdx.x;
    int rb = blockIdx.x * 16;
    // stage 16 embedding rows: 16*512 = 8192 floats = 2048 float4
#pragma unroll
    for (int i = 0; i < 8; i++) {
        int idx = tid + i * 256;           // float4 index, 0..2047
        int r = idx >> 7, q = idx & 127;
        ((float4*)xs[r])[q] = ((const float4*)(emb + (size_t)dec[rb + r] * E_))[q];
    }
    __syncthreads();
    float acc[16];
#pragma unroll
    for (int r = 0; r < 16; r++) acc[r] = 0.f;
    for (int e = 0; e < E_; e += 4) {
        float w0 = Wx[(e + 0) * G_ + tid];
        float w1 = Wx[(e + 1) * G_ + tid];
        float w2 = Wx[(e + 2) * G_ + tid];
        float w3 = Wx[(e + 3) * G_ + tid];
#pragma unroll
        for (int r = 0; r < 16; r++) {
            float4 xv = *(const float4*)&xs[r][e];
            acc[r] += xv.x * w0 + xv.y * w1 + xv.z * w2 + xv.w * w3;
        }
    }
    float bv = bias[tid];
#pragma unroll
    for (int r = 0; r < 16; r++)
        xz[(size_t)(rb + r) * G_ + tid] = acc[r] + bv;
}

// ---------------------------------------------------------------------------
// K2: LSTM scan. one block per batch element, 256 threads (one per gate-unit).
// recurrent dot vectorized via float4 LDS reads (on the 128-step serial path).
// ---------------------------------------------------------------------------
__global__ void lstm_kernel(const float* __restrict__ xz,
                            const float* __restrict__ h0,
                            const float* __restrict__ c0,
                            const float* __restrict__ Wh,
                            float* __restrict__ feat,
                            float* __restrict__ hT,
                            float* __restrict__ cT) {
    int b = blockIdx.x;
    int g = threadIdx.x;   // 0..255
    float w[U_];
#pragma unroll
    for (int u = 0; u < U_; u++) w[u] = Wh[u * G_ + g];
    __shared__ float h[U_];
    __shared__ float c[U_];
    __shared__ float z[G_];
    if (g < U_) { h[g] = h0[b * U_ + g]; c[g] = c0[b * U_ + g]; }
    __syncthreads();
    const float* xzb = xz + (size_t)b * T_ * G_;
    for (int t = 0; t < T_; t++) {
        float acc = xzb[t * G_ + g];
#pragma unroll
        for (int u4 = 0; u4 < U_ / 4; u4++) {
            float4 hv = *(const float4*)&h[u4 * 4];
            acc += hv.x * w[u4 * 4 + 0] + hv.y * w[u4 * 4 + 1] +
                   hv.z * w[u4 * 4 + 2] + hv.w * w[u4 * 4 + 3];
        }
        z[g] = acc;
        __syncthreads();
        if (g < U_) {
            float iv = 1.f / (1.f + expf(-z[g]));
            float fv = 1.f / (1.f + expf(-z[U_ + g]));
            float gv = tanhf(z[2 * U_ + g]);
            float ov = 1.f / (1.f + expf(-z[3 * U_ + g]));
            float cn = fv * c[g] + iv * gv;
            float hn = ov * tanhf(cn);
            c[g] = cn; h[g] = hn;
            feat[((size_t)b * T_ + t) * 2 * U_ + g] = hn;
        }
        __syncthreads();
    }
    if (g < U_) { hT[b * U_ + g] = h[g]; cT[b * U_ + g] = c[g]; }
}

// ---------------------------------------------------------------------------
// K3: Luong attention per (b,t). query = h_{t-1} (h0 at t=0).
// ---------------------------------------------------------------------------
__global__ void attn_kernel(const float* __restrict__ enc,
                            const float* __restrict__ h0,
                            float* __restrict__ feat) {
    int row = blockIdx.x;          // b*T + t
    int b = row >> 7;
    int t = row & (T_ - 1);
    int tid = threadIdx.x;         // 0..127
    __shared__ float kv[U_];
    __shared__ float at[TE_];
    __shared__ float red[TE_];
    if (tid < U_)
        kv[tid] = (t == 0) ? h0[b * U_ + tid] : feat[(size_t)(row - 1) * 2 * U_ + tid];
    __syncthreads();
    const float* encb = enc + (size_t)b * TE_ * U_;
    float s = 0.f;
    const float4* e4 = (const float4*)(encb + tid * U_);
#pragma unroll
    for (int u4 = 0; u4 < U_ / 4; u4++) {
        float4 ev = e4[u4];
        s += ev.x * kv[u4 * 4 + 0] + ev.y * kv[u4 * 4 + 1] +
             ev.z * kv[u4 * 4 + 2] + ev.w * kv[u4 * 4 + 3];
    }
    red[tid] = s;
    __syncthreads();
    for (int off = 64; off > 0; off >>= 1) {
        if (tid < off) red[tid] = fmaxf(red[tid], red[tid + off]);
        __syncthreads();
    }
    float m = red[0];
    __syncthreads();
    float e = expf(s - m);
    at[tid] = e;
    red[tid] = e;
    __syncthreads();
    for (int off = 64; off > 0; off >>= 1) {
        if (tid < off) red[tid] += red[tid + off];
        __syncthreads();
    }
    float inv_sum = 1.f / red[0];
    __syncthreads();
    if (tid < U_) {
        float cacc = 0.f;
#pragma unroll 4
        for (int sx = 0; sx < TE_; sx++)
            cacc += at[sx] * encb[sx * U_ + tid];
        feat[(size_t)row * 2 * U_ + U_ + tid] = cacc * inv_sum;
    }
}

// ---------------------------------------------------------------------------
// K3b: feat fp32 -> bf16
// ---------------------------------------------------------------------------
__global__ void feat_to_bf16(const float* __restrict__ feat,
                             unsigned short* __restrict__ fb) {
    int i = blockIdx.x * 256 + threadIdx.x;   // float4 index, 131072 total
    float4 v = ((const float4*)feat)[i];
    u16x4 o;
    o.x = f2bf(v.x); o.y = f2bf(v.y); o.z = f2bf(v.z); o.w = f2bf(v.w);
    *(u16x4*)(fb + (size_t)i * 4) = o;
}

// ---------------------------------------------------------------------------
// K3c: Wd [128][32000] fp32 -> Wd_t [32000][128] bf16 (transposed)
// block: 64 n-cols, grid 500
// ---------------------------------------------------------------------------
__global__ void wd_transpose(const float* __restrict__ Wd,
                             unsigned short* __restrict__ wdt) {
    __shared__ float t[128][65];               // 33.3 KB
    int tid = threadIdx.x;
    int nb = blockIdx.x * 64;
#pragma unroll
    for (int i = 0; i < 32; i++) {
        int idx = tid + i * 256;               // 0..8191
        int k = idx >> 6, n = idx & 63;
        t[k][n] = Wd[(size_t)k * V_ + nb + n];
    }
    __syncthreads();
    int n = tid >> 2, kq = tid & 3;            // 64 rows x 4 k-quarters(32 each)
#pragma unroll
    for (int g = 0; g < 4; g++) {
        short8x s;
#pragma unroll
        for (int j = 0; j < 8; j++)
            s[j] = (short)f2bf(t[kq * 32 + g * 8 + j][n]);
        *(short8x*)(wdt + (size_t)(nb + n) * 128 + kq * 32 + g * 8) = s;
    }
}

// ---------------------------------------------------------------------------
// XCD-locality swizzle for the two GEMM passes.
// wdt is 8.2 MB; per-XCD L2 is 4 MB. Old grid (64 rowblk, 25 colblk) made
// every XCD touch all of wdt (round-robin dispatch) -> L2 thrash, B-panels
// served from L3. New: 1-D grid of 1600, col-major work order chunked so
// XCD i (= L % 8) owns a contiguous 200-block range = ~4000 columns = 1 MB
// of wdt -> L2-resident. Bijective (1600 % 8 == 0).
// ---------------------------------------------------------------------------
__device__ inline void gemm_block_map(int L, int& rowblk, int& colblk) {
    int W = (L & 7) * 200 + (L >> 3);   // contiguous work range per XCD
    colblk = W >> 6;                    // 0..24  (col-panel of 1280)
    rowblk = W & 63;                    // 0..63  (row-block of 64)
}

// ---------------------------------------------------------------------------
// K4a: GEMM pass 1 — per-row sum(exp(logit)) partials, nothing materialized.
// 1600 blocks (swizzled). 256 thr = 4 waves,
// wave handles 16 rows x 128 cols per chunk, 10 chunks.
// MFMA 16x16x32 bf16; A & B fragments are direct 16B coalesced loads.
// ---------------------------------------------------------------------------
__global__ void gemm_stats(const unsigned short* __restrict__ fb,
                           const unsigned short* __restrict__ wdt,
                           const float* __restrict__ bd,
                           float* __restrict__ partial) {
    int rowblk, cb;
    gemm_block_map(blockIdx.x, rowblk, cb);
    int tid = threadIdx.x;
    int lane = tid & 63, wave = tid >> 6;
    int lrow = lane & 15, quad = lane >> 4;
    int rowbase = rowblk * 64 + wave * 16;
    int col0 = cb * 1280;

    short8x a[4];
    const unsigned short* ap = fb + (size_t)(rowbase + lrow) * 128 + quad * 8;
#pragma unroll
    for (int k = 0; k < 4; k++) a[k] = *(const short8x*)(ap + k * 32);

    float s[4] = {0.f, 0.f, 0.f, 0.f};
    for (int ch = 0; ch < 10; ch++) {
        int cc = col0 + ch * 128;
        f32x4 acc[8];
#pragma unroll
        for (int ct = 0; ct < 8; ct++) acc[ct] = {0.f, 0.f, 0.f, 0.f};
        const unsigned short* bp = wdt + (size_t)(cc + lrow) * 128 + quad * 8;
#pragma unroll
        for (int ct = 0; ct < 8; ct++) {
#pragma unroll
            for (int k = 0; k < 4; k++) {
                short8x b = *(const short8x*)(bp + (size_t)ct * 16 * 128 + k * 32);
                acc[ct] = __builtin_amdgcn_mfma_f32_16x16x32_bf16(a[k], b, acc[ct], 0, 0, 0);
            }
        }
#pragma unroll
        for (int ct = 0; ct < 8; ct++) {
            float bdv = bd[cc + ct * 16 + lrow];
#pragma unroll
            for (int r = 0; r < 4; r++)
                s[r] += __expf(acc[ct][r] + bdv);
        }
    }
    // reduce across the 16 lanes holding the same rows (lane-xor 1,2,4,8)
#pragma unroll
    for (int r = 0; r < 4; r++) {
        float v = s[r];
        v += __shfl_xor(v, 1);
        v += __shfl_xor(v, 2);
        v += __shfl_xor(v, 4);
        v += __shfl_xor(v, 8);
        if (lrow == 0)
            partial[(size_t)(rowbase + quad * 4 + r) * 25 + cb] = v;
    }
}

// ---------------------------------------------------------------------------
// K4b: merge partials -> inv_s[row]
// ---------------------------------------------------------------------------
__global__ void merge_stats(const float* __restrict__ partial,
                            float* __restrict__ inv_s) {
    int r = blockIdx.x * 256 + threadIdx.x;   // 4096
    float s = 0.f;
#pragma unroll
    for (int i = 0; i < 25; i++) s += partial[(size_t)r * 25 + i];
    inv_s[r] = 1.f / s;
}

// ---------------------------------------------------------------------------
// K4c: GEMM pass 2 — recompute logits, write exp(l)*inv_s via LDS transpose
// so global stores are 512B-contiguous float4 runs. Output stores are
// NONTEMPORAL (via clang ext-vector f32x4, not HIP_vector_type): the 524 MB
// streaming write must not allocate in L2 and evict the L2-resident wdt.
// ---------------------------------------------------------------------------
__global__ void gemm_norm(const unsigned short* __restrict__ fb,
                          const unsigned short* __restrict__ wdt,
                          const float* __restrict__ bd,
                          const float* __restrict__ inv_s,
                          float* __restrict__ out) {
    __shared__ float lds[64 * 132];            // 33.8 KB, pad 132 breaks conflicts
    int rowblkI, cbI;
    gemm_block_map(blockIdx.x, rowblkI, cbI);
    int tid = threadIdx.x;
    int lane = tid & 63, wave = tid >> 6;
    int lrow = lane & 15, quad = lane >> 4;
    int rowblk = rowblkI * 64;
    int rowbase = rowblk + wave * 16;
    int col0 = cbI * 1280;

    short8x a[4];
    const unsigned short* ap = fb + (size_t)(rowbase + lrow) * 128 + quad * 8;
#pragma unroll
    for (int k = 0; k < 4; k++) a[k] = *(const short8x*)(ap + k * 32);

    float inv[4];
#pragma unroll
    for (int r = 0; r < 4; r++) inv[r] = inv_s[rowbase + quad * 4 + r];

    for (int ch = 0; ch < 10; ch++) {
        int cc = col0 + ch * 128;
        f32x4 acc[8];
#pragma unroll
        for (int ct = 0; ct < 8; ct++) acc[ct] = {0.f, 0.f, 0.f, 0.f};
        const unsigned short* bp = wdt + (size_t)(cc + lrow) * 128 + quad * 8;
#pragma unroll
        for (int ct = 0; ct < 8; ct++) {
#pragma unroll
            for (int k = 0; k < 4; k++) {
                short8x b = *(const short8x*)(bp + (size_t)ct * 16 * 128 + k * 32);
                acc[ct] = __builtin_amdgcn_mfma_f32_16x16x32_bf16(a[k], b, acc[ct], 0, 0, 0);
            }
        }
        __syncthreads();   // previous chunk's LDS reads complete
#pragma unroll
        for (int ct = 0; ct < 8; ct++) {
            float bdv = bd[cc + ct * 16 + lrow];
#pragma unroll
            for (int r = 0; r < 4; r++)
                lds[(wave * 16 + quad * 4 + r) * 132 + ct * 16 + lrow] =
                    __expf(acc[ct][r] + bdv) * inv[r];
        }
        __syncthreads();
        // cooperative coalesced store: 64 rows x 128 cols = 2048 float4
#pragma unroll
        for (int i = 0; i < 8; i++) {
            int idx = tid + i * 256;
            int r = idx >> 5, c4 = idx & 31;
            f32x4 v = *(f32x4*)&lds[r * 132 + c4 * 4];
            __builtin_nontemporal_store(v,
                (f32x4*)(out + (size_t)(rowblk + r) * V_ + cc + c4 * 4));
        }
    }
}

extern "C" void kernel_launch(void* const* d_in, const int* in_sizes, int n_in,
                              void* d_out, int out_size, void* d_ws, size_t ws_size,
                              hipStream_t stream) {
    const float* enc  = (const float*)d_in[0];
    const int*   dec  = (const int*)d_in[1];
    const float* h0   = (const float*)d_in[2];
    const float* c0   = (const float*)d_in[3];
    const float* emb  = (const float*)d_in[4];
    const float* Wx   = (const float*)d_in[5];
    const float* Wh   = (const float*)d_in[6];
    const float* bias = (const float*)d_in[7];
    const float* Wd   = (const float*)d_in[8];
    const float* bd   = (const float*)d_in[9];
    float* out = (float*)d_out;
    float* ws  = (float*)d_ws;

    const int NROW = B_ * T_;                       // 4096
    float* xz      = ws;                            // 1,048,576 f
    float* feat    = xz + (size_t)NROW * G_;        //   524,288 f
    float* partial = feat + (size_t)NROW * 2 * U_;  //   102,400 f
    float* inv_s   = partial + (size_t)NROW * 25;   //     4,096 f
    unsigned short* fb  = (unsigned short*)(inv_s + NROW);          // 524,288 u16
    unsigned short* wdt = (unsigned short*)(fb + (size_t)NROW * 2 * U_); // 4,096,000 u16
    float* hT = out + (size_t)NROW * V_;
    float* cT = hT + B_ * U_;

    wd_transpose<<<dim3(V_ / 64), 256, 0, stream>>>(Wd, wdt);
    embed_xz_kernel<<<dim3(NROW / 16), 256, 0, stream>>>(dec, emb, Wx, bias, xz);
    lstm_kernel<<<dim3(B_), 256, 0, stream>>>(xz, h0, c0, Wh, feat, hT, cT);
    attn_kernel<<<dim3(NROW), 128, 0, stream>>>(enc, h0, feat);
    feat_to_bf16<<<dim3(NROW * 2 * U_ / 1024), 256, 0, stream>>>(feat, fb);
    gemm_stats<<<dim3(1600), 256, 0, stream>>>(fb, wdt, bd, partial);
    merge_stats<<<dim3(NROW / 256), 256, 0, stream>>>(partial, inv_s);
    gemm_norm<<<dim3(1600), 256, 0, stream>>>(fb, wdt, bd, inv_s, out);
}

// Round 3
// 1060.054 us; speedup vs baseline: 1.1848x; 1.1528x over previous
//
#include <hip/hip_runtime.h>
#include <hip/hip_bf16.h>
#include <math.h>

// Problem constants
#define B_   32
#define T_   128
#define TE_  128
#define U_   64
#define E_   512
#define V_   32000
#define G_   256   // 4*U

typedef __attribute__((ext_vector_type(8))) short  short8x;
typedef __attribute__((ext_vector_type(4))) float  f32x4;
typedef __attribute__((ext_vector_type(4))) unsigned short u16x4;

__device__ inline unsigned short f2bf(float x) {
    union { float f; unsigned int u; } v; v.f = x;
    unsigned int u = v.u;
    u = (u + 0x7FFFu + ((u >> 16) & 1u)) >> 16;   // round-to-nearest-even
    return (unsigned short)u;
}

// ---------------------------------------------------------------------------
// K1: xz[row, g] = sum_e emb[dec[row], e] * Wx[e, g] + bias[g]
// ---------------------------------------------------------------------------
__global__ void embed_xz_kernel(const int* __restrict__ dec,
                                const float* __restrict__ emb,
                                const float* __restrict__ Wx,
                                const float* __restrict__ bias,
                                float* __restrict__ xz) {
    __shared__ float xs[16][E_];           // 32 KB
    int tid = threadIdx.x;
    int rb = blockIdx.x * 16;
#pragma unroll
    for (int i = 0; i < 8; i++) {
        int idx = tid + i * 256;           // float4 index, 0..2047
        int r = idx >> 7, q = idx & 127;
        ((float4*)xs[r])[q] = ((const float4*)(emb + (size_t)dec[rb + r] * E_))[q];
    }
    __syncthreads();
    float acc[16];
#pragma unroll
    for (int r = 0; r < 16; r++) acc[r] = 0.f;
    for (int e = 0; e < E_; e += 4) {
        float w0 = Wx[(e + 0) * G_ + tid];
        float w1 = Wx[(e + 1) * G_ + tid];
        float w2 = Wx[(e + 2) * G_ + tid];
        float w3 = Wx[(e + 3) * G_ + tid];
#pragma unroll
        for (int r = 0; r < 16; r++) {
            float4 xv = *(const float4*)&xs[r][e];
            acc[r] += xv.x * w0 + xv.y * w1 + xv.z * w2 + xv.w * w3;
        }
    }
    float bv = bias[tid];
#pragma unroll
    for (int r = 0; r < 16; r++)
        xz[(size_t)(rb + r) * G_ + tid] = acc[r] + bv;
}

// ---------------------------------------------------------------------------
// K2: LSTM scan. one block per batch element, 256 threads (one per gate-unit).
// 4 independent FMA chains (16-deep instead of 64-deep) on the serial path;
// next-step xz prefetched before the barriers (32 blocks -> no TLP to hide
// the ~300-900cy global latency otherwise).
// Writes h as fp32 (attn queries) AND bf16 (GEMM A operand) -> feat_to_bf16
// kernel eliminated.
// ---------------------------------------------------------------------------
__global__ void lstm_kernel(const float* __restrict__ xz,
                            const float* __restrict__ h0,
                            const float* __restrict__ c0,
                            const float* __restrict__ Wh,
                            float* __restrict__ feat,
                            unsigned short* __restrict__ fb,
                            float* __restrict__ hT,
                            float* __restrict__ cT) {
    int b = blockIdx.x;
    int g = threadIdx.x;   // 0..255
    float w[U_];
#pragma unroll
    for (int u = 0; u < U_; u++) w[u] = Wh[u * G_ + g];
    __shared__ float h[U_];
    __shared__ float c[U_];
    __shared__ float z[G_];
    if (g < U_) { h[g] = h0[b * U_ + g]; c[g] = c0[b * U_ + g]; }
    const float* xzb = xz + (size_t)b * T_ * G_;
    float xznext = xzb[g];                 // prefetch t=0
    __syncthreads();
    for (int t = 0; t < T_; t++) {
        float ac0 = xznext, ac1 = 0.f, ac2 = 0.f, ac3 = 0.f;
        // prefetch next step's xz; latency hides under dot + barriers
        int tn = (t + 1 < T_) ? t + 1 : t;
        xznext = xzb[tn * G_ + g];
#pragma unroll
        for (int u4 = 0; u4 < 16; u4 += 4) {
            float4 h0v = *(const float4*)&h[(u4 + 0) * 4];
            float4 h1v = *(const float4*)&h[(u4 + 1) * 4];
            float4 h2v = *(const float4*)&h[(u4 + 2) * 4];
            float4 h3v = *(const float4*)&h[(u4 + 3) * 4];
            ac0 += h0v.x * w[(u4+0)*4+0] + h0v.y * w[(u4+0)*4+1] +
                   h0v.z * w[(u4+0)*4+2] + h0v.w * w[(u4+0)*4+3];
            ac1 += h1v.x * w[(u4+1)*4+0] + h1v.y * w[(u4+1)*4+1] +
                   h1v.z * w[(u4+1)*4+2] + h1v.w * w[(u4+1)*4+3];
            ac2 += h2v.x * w[(u4+2)*4+0] + h2v.y * w[(u4+2)*4+1] +
                   h2v.z * w[(u4+2)*4+2] + h2v.w * w[(u4+2)*4+3];
            ac3 += h3v.x * w[(u4+3)*4+0] + h3v.y * w[(u4+3)*4+1] +
                   h3v.z * w[(u4+3)*4+2] + h3v.w * w[(u4+3)*4+3];
        }
        z[g] = (ac0 + ac1) + (ac2 + ac3);
        __syncthreads();
        if (g < U_) {
            float iv = 1.f / (1.f + expf(-z[g]));
            float fv = 1.f / (1.f + expf(-z[U_ + g]));
            float gv = tanhf(z[2 * U_ + g]);
            float ov = 1.f / (1.f + expf(-z[3 * U_ + g]));
            float cn = fv * c[g] + iv * gv;
            float hn = ov * tanhf(cn);
            c[g] = cn; h[g] = hn;
            size_t row = (size_t)b * T_ + t;
            feat[row * 2 * U_ + g] = hn;           // fp32 for attn queries
            fb[row * 2 * U_ + g] = f2bf(hn);       // bf16 for GEMM
        }
        __syncthreads();
    }
    if (g < U_) { hT[b * U_ + g] = h[g]; cT[b * U_ + g] = c[g]; }
}

// ---------------------------------------------------------------------------
// K3: Luong attention per (b,t). query = h_{t-1} (h0 at t=0).
// ctx written directly as bf16 into fb (fp32 ctx never materialized).
// ---------------------------------------------------------------------------
__global__ void attn_kernel(const float* __restrict__ enc,
                            const float* __restrict__ h0,
                            const float* __restrict__ feat,
                            unsigned short* __restrict__ fb) {
    int row = blockIdx.x;          // b*T + t
    int b = row >> 7;
    int t = row & (T_ - 1);
    int tid = threadIdx.x;         // 0..127
    __shared__ float kv[U_];
    __shared__ float at[TE_];
    __shared__ float red[TE_];
    if (tid < U_)
        kv[tid] = (t == 0) ? h0[b * U_ + tid] : feat[(size_t)(row - 1) * 2 * U_ + tid];
    __syncthreads();
    const float* encb = enc + (size_t)b * TE_ * U_;
    float s = 0.f;
    const float4* e4 = (const float4*)(encb + tid * U_);
#pragma unroll
    for (int u4 = 0; u4 < U_ / 4; u4++) {
        float4 ev = e4[u4];
        s += ev.x * kv[u4 * 4 + 0] + ev.y * kv[u4 * 4 + 1] +
             ev.z * kv[u4 * 4 + 2] + ev.w * kv[u4 * 4 + 3];
    }
    red[tid] = s;
    __syncthreads();
    for (int off = 64; off > 0; off >>= 1) {
        if (tid < off) red[tid] = fmaxf(red[tid], red[tid + off]);
        __syncthreads();
    }
    float m = red[0];
    __syncthreads();
    float e = expf(s - m);
    at[tid] = e;
    red[tid] = e;
    __syncthreads();
    for (int off = 64; off > 0; off >>= 1) {
        if (tid < off) red[tid] += red[tid + off];
        __syncthreads();
    }
    float inv_sum = 1.f / red[0];
    __syncthreads();
    if (tid < U_) {
        float cacc = 0.f;
#pragma unroll 4
        for (int sx = 0; sx < TE_; sx++)
            cacc += at[sx] * encb[sx * U_ + tid];
        fb[(size_t)row * 2 * U_ + U_ + tid] = f2bf(cacc * inv_sum);
    }
}

// ---------------------------------------------------------------------------
// K3c: Wd [128][32000] fp32 -> Wd_t [32000][128] bf16 (transposed)
// ---------------------------------------------------------------------------
__global__ void wd_transpose(const float* __restrict__ Wd,
                             unsigned short* __restrict__ wdt) {
    __shared__ float t[128][65];               // 33.3 KB
    int tid = threadIdx.x;
    int nb = blockIdx.x * 64;
#pragma unroll
    for (int i = 0; i < 32; i++) {
        int idx = tid + i * 256;               // 0..8191
        int k = idx >> 6, n = idx & 63;
        t[k][n] = Wd[(size_t)k * V_ + nb + n];
    }
    __syncthreads();
    int n = tid >> 2, kq = tid & 3;            // 64 rows x 4 k-quarters(32 each)
#pragma unroll
    for (int g = 0; g < 4; g++) {
        short8x s;
#pragma unroll
        for (int j = 0; j < 8; j++)
            s[j] = (short)f2bf(t[kq * 32 + g * 8 + j][n]);
        *(short8x*)(wdt + (size_t)(nb + n) * 128 + kq * 32 + g * 8) = s;
    }
}

// ---------------------------------------------------------------------------
// GEMM grid: 128-row blocks x 1280-col panels -> 32 x 25 = 800 blocks.
// Each wave owns 2x16-row A-tiles so every B fragment feeds 2 MFMAs:
// halves the L2 B-panel traffic (524->262 MB/pass), L2-BW ceiling 550->1100 TF.
// XCD chunking: XCD i owns 100 contiguous work items, col-major (rowblk
// fastest) so one 327 KB col-panel stays hot per XCD. Bijective (800%8==0).
// ---------------------------------------------------------------------------
__device__ inline void gemm_block_map(int L, int& rowblk, int& colblk) {
    int W = (L & 7) * 100 + (L >> 3);
    colblk = W >> 5;                    // 0..24
    rowblk = W & 31;                    // 0..31
}

// ---------------------------------------------------------------------------
// K4a: GEMM pass 1 — per-row sum(exp(logit)) partials.
// ---------------------------------------------------------------------------
__global__ void gemm_stats(const unsigned short* __restrict__ fb,
                           const unsigned short* __restrict__ wdt,
                           const float* __restrict__ bd,
                           float* __restrict__ partial) {
    int rowblk, cb;
    gemm_block_map(blockIdx.x, rowblk, cb);
    int tid = threadIdx.x;
    int lane = tid & 63, wave = tid >> 6;
    int lrow = lane & 15, quad = lane >> 4;
    int rowbase = rowblk * 128 + wave * 32;
    int col0 = cb * 1280;

    short8x a[2][4];
#pragma unroll
    for (int rt = 0; rt < 2; rt++) {
        const unsigned short* ap = fb + (size_t)(rowbase + rt * 16 + lrow) * 128 + quad * 8;
#pragma unroll
        for (int k = 0; k < 4; k++) a[rt][k] = *(const short8x*)(ap + k * 32);
    }

    float s[2][4] = {{0.f,0.f,0.f,0.f},{0.f,0.f,0.f,0.f}};
    for (int ch = 0; ch < 10; ch++) {
        int cc = col0 + ch * 128;
        f32x4 acc[2][8];
#pragma unroll
        for (int rt = 0; rt < 2; rt++)
#pragma unroll
            for (int ct = 0; ct < 8; ct++) acc[rt][ct] = {0.f, 0.f, 0.f, 0.f};
        const unsigned short* bp = wdt + (size_t)(cc + lrow) * 128 + quad * 8;
#pragma unroll
        for (int ct = 0; ct < 8; ct++) {
#pragma unroll
            for (int k = 0; k < 4; k++) {
                short8x b = *(const short8x*)(bp + (size_t)ct * 16 * 128 + k * 32);
                acc[0][ct] = __builtin_amdgcn_mfma_f32_16x16x32_bf16(a[0][k], b, acc[0][ct], 0, 0, 0);
                acc[1][ct] = __builtin_amdgcn_mfma_f32_16x16x32_bf16(a[1][k], b, acc[1][ct], 0, 0, 0);
            }
        }
#pragma unroll
        for (int ct = 0; ct < 8; ct++) {
            float bdv = bd[cc + ct * 16 + lrow];
#pragma unroll
            for (int rt = 0; rt < 2; rt++)
#pragma unroll
                for (int r = 0; r < 4; r++)
                    s[rt][r] += __expf(acc[rt][ct][r] + bdv);
        }
    }
#pragma unroll
    for (int rt = 0; rt < 2; rt++)
#pragma unroll
        for (int r = 0; r < 4; r++) {
            float v = s[rt][r];
            v += __shfl_xor(v, 1);
            v += __shfl_xor(v, 2);
            v += __shfl_xor(v, 4);
            v += __shfl_xor(v, 8);
            if (lrow == 0)
                partial[(size_t)(rowbase + rt * 16 + quad * 4 + r) * 25 + cb] = v;
        }
}

// ---------------------------------------------------------------------------
// K4b: merge partials -> inv_s[row]
// ---------------------------------------------------------------------------
__global__ void merge_stats(const float* __restrict__ partial,
                            float* __restrict__ inv_s) {
    int r = blockIdx.x * 256 + threadIdx.x;   // 4096
    float s = 0.f;
#pragma unroll
    for (int i = 0; i < 25; i++) s += partial[(size_t)r * 25 + i];
    inv_s[r] = 1.f / s;
}

// ---------------------------------------------------------------------------
// K4c: GEMM pass 2 — recompute logits, write exp(l)*inv_s via LDS transpose.
// 128-row blocks; LDS transpose done in two 64-row phases (34 KB buffer).
// Nontemporal stores: streaming 524 MB write must not evict L2-resident wdt.
// ---------------------------------------------------------------------------
__global__ void gemm_norm(const unsigned short* __restrict__ fb,
                          const unsigned short* __restrict__ wdt,
                          const float* __restrict__ bd,
                          const float* __restrict__ inv_s,
                          float* __restrict__ out) {
    __shared__ float lds[64 * 132];            // 33.8 KB
    int rowblkI, cbI;
    gemm_block_map(blockIdx.x, rowblkI, cbI);
    int tid = threadIdx.x;
    int lane = tid & 63, wave = tid >> 6;
    int lrow = lane & 15, quad = lane >> 4;
    int rowblk = rowblkI * 128;
    int rowbase = rowblk + wave * 32;
    int col0 = cbI * 1280;

    short8x a[2][4];
#pragma unroll
    for (int rt = 0; rt < 2; rt++) {
        const unsigned short* ap = fb + (size_t)(rowbase + rt * 16 + lrow) * 128 + quad * 8;
#pragma unroll
        for (int k = 0; k < 4; k++) a[rt][k] = *(const short8x*)(ap + k * 32);
    }

    float inv[2][4];
#pragma unroll
    for (int rt = 0; rt < 2; rt++)
#pragma unroll
        for (int r = 0; r < 4; r++)
            inv[rt][r] = inv_s[rowbase + rt * 16 + quad * 4 + r];

    for (int ch = 0; ch < 10; ch++) {
        int cc = col0 + ch * 128;
        f32x4 acc[2][8];
#pragma unroll
        for (int rt = 0; rt < 2; rt++)
#pragma unroll
            for (int ct = 0; ct < 8; ct++) acc[rt][ct] = {0.f, 0.f, 0.f, 0.f};
        const unsigned short* bp = wdt + (size_t)(cc + lrow) * 128 + quad * 8;
#pragma unroll
        for (int ct = 0; ct < 8; ct++) {
#pragma unroll
            for (int k = 0; k < 4; k++) {
                short8x b = *(const short8x*)(bp + (size_t)ct * 16 * 128 + k * 32);
                acc[0][ct] = __builtin_amdgcn_mfma_f32_16x16x32_bf16(a[0][k], b, acc[0][ct], 0, 0, 0);
                acc[1][ct] = __builtin_amdgcn_mfma_f32_16x16x32_bf16(a[1][k], b, acc[1][ct], 0, 0, 0);
            }
        }
#pragma unroll
        for (int rt = 0; rt < 2; rt++) {
            __syncthreads();   // previous phase's LDS reads complete
#pragma unroll
            for (int ct = 0; ct < 8; ct++) {
                float bdv = bd[cc + ct * 16 + lrow];
#pragma unroll
                for (int r = 0; r < 4; r++)
                    lds[(wave * 16 + quad * 4 + r) * 132 + ct * 16 + lrow] =
                        __expf(acc[rt][ct][r] + bdv) * inv[rt][r];
            }
            __syncthreads();
            // cooperative coalesced store: 64 LDS rows -> out rows
            // l = wave*16 + rowInTile  ->  out row = rowblk + wave*32 + rt*16 + rowInTile
#pragma unroll
            for (int i = 0; i < 8; i++) {
                int idx = tid + i * 256;
                int l = idx >> 5, c4 = idx & 31;
                int orow = rowblk + (l >> 4) * 32 + rt * 16 + (l & 15);
                f32x4 v = *(f32x4*)&lds[l * 132 + c4 * 4];
                __builtin_nontemporal_store(v,
                    (f32x4*)(out + (size_t)orow * V_ + cc + c4 * 4));
            }
        }
    }
}

extern "C" void kernel_launch(void* const* d_in, const int* in_sizes, int n_in,
                              void* d_out, int out_size, void* d_ws, size_t ws_size,
                              hipStream_t stream) {
    const float* enc  = (const float*)d_in[0];
    const int*   dec  = (const int*)d_in[1];
    const float* h0   = (const float*)d_in[2];
    const float* c0   = (const float*)d_in[3];
    const float* emb  = (const float*)d_in[4];
    const float* Wx   = (const float*)d_in[5];
    const float* Wh   = (const float*)d_in[6];
    const float* bias = (const float*)d_in[7];
    const float* Wd   = (const float*)d_in[8];
    const float* bd   = (const float*)d_in[9];
    float* out = (float*)d_out;
    float* ws  = (float*)d_ws;

    const int NROW = B_ * T_;                       // 4096
    float* xz      = ws;                            // 1,048,576 f
    float* feat    = xz + (size_t)NROW * G_;        //   524,288 f
    float* partial = feat + (size_t)NROW * 2 * U_;  //   102,400 f
    float* inv_s   = partial + (size_t)NROW * 25;   //     4,096 f
    unsigned short* fb  = (unsigned short*)(inv_s + NROW);          // 524,288 u16
    unsigned short* wdt = (unsigned short*)(fb + (size_t)NROW * 2 * U_); // 4,096,000 u16
    float* hT = out + (size_t)NROW * V_;
    float* cT = hT + B_ * U_;

    wd_transpose<<<dim3(V_ / 64), 256, 0, stream>>>(Wd, wdt);
    embed_xz_kernel<<<dim3(NROW / 16), 256, 0, stream>>>(dec, emb, Wx, bias, xz);
    lstm_kernel<<<dim3(B_), 256, 0, stream>>>(xz, h0, c0, Wh, feat, fb, hT, cT);
    attn_kernel<<<dim3(NROW), 128, 0, stream>>>(enc, h0, feat, fb);
    gemm_stats<<<dim3(800), 256, 0, stream>>>(fb, wdt, bd, partial);
    merge_stats<<<dim3(NROW / 256), 256, 0, stream>>>(partial, inv_s);
    gemm_norm<<<dim3(800), 256, 0, stream>>>(fb, wdt, bd, inv_s, out);
}